// Round 1
// 320.094 us; speedup vs baseline: 1.0284x; 1.0284x over previous
//
#include <hip/hip_runtime.h>
#include <hip/hip_bf16.h>

typedef unsigned short u16;
typedef __attribute__((ext_vector_type(4))) float f32x4;
typedef __attribute__((ext_vector_type(4))) unsigned int u32x4;
typedef __attribute__((ext_vector_type(4))) unsigned short u16x4;
typedef __attribute__((ext_vector_type(8))) unsigned short u16x8;
typedef __attribute__((ext_vector_type(8))) __bf16 bf16x8;

__device__ inline float u2f(u16 u) {
    union { unsigned int i; float f; } x; x.i = ((unsigned int)u) << 16; return x.f;
}
__device__ inline u16 f2u(float f) {
    __hip_bfloat16 b = __float2bfloat16(f);
    return *reinterpret_cast<u16*>(&b);
}
__device__ inline f32x4 mfma16(bf16x8 a, bf16x8 b, f32x4 c) {
    return __builtin_amdgcn_mfma_f32_16x16x32_bf16(a, b, c, 0, 0, 0);
}
__device__ inline void gload_lds16(const u16* g, u16* l) {
    __builtin_amdgcn_global_load_lds(
        (const __attribute__((address_space(1))) unsigned int*)g,
        (__attribute__((address_space(3))) unsigned int*)l, 16, 0, 0);
}

// ---------------------------------------------------------------------------
// Merged projection GEMMs: one dispatch for all four x@W+b (relu) projections.
// grid (8, 320): y<32 lig->l1v(mode1), y<64 lig->l2t(mode3),
// y<192 prot->p1v(mode1), else prot->p2t(mode3). 128x128 tile, K=128.
// ---------------------------------------------------------------------------
__global__ __launch_bounds__(256)
void proj_kernel(const u16* __restrict__ ligb, const u16* __restrict__ protb,
                 const u16* __restrict__ Wl1t, const u16* __restrict__ Wl2t,
                 const u16* __restrict__ Wp1t, const u16* __restrict__ Wp2t,
                 const float* __restrict__ bl1, const float* __restrict__ bl2,
                 const float* __restrict__ bp1, const float* __restrict__ bp2,
                 u16* __restrict__ l1v, u16* __restrict__ l2tv,
                 u16* __restrict__ p1v, u16* __restrict__ p2tv)
{
    __shared__ __align__(16) u16 As[128 * 64];
    __shared__ __align__(16) u16 Bs[128 * 64];
    const int y = blockIdx.y;
    const u16* A; const u16* B; const float* bias; u16* Out;
    int mode, logL, my;
    if (y < 32)       { A = ligb;  B = Wl1t; bias = bl1; Out = l1v;  mode = 1; logL = 8;  my = y; }
    else if (y < 64)  { A = ligb;  B = Wl2t; bias = bl2; Out = l2tv; mode = 3; logL = 8;  my = y - 32; }
    else if (y < 192) { A = protb; B = Wp1t; bias = bp1; Out = p1v;  mode = 1; logL = 10; my = y - 64; }
    else              { A = protb; B = Wp2t; bias = bp2; Out = p2tv; mode = 3; logL = 10; my = y - 192; }
    const int n0 = blockIdx.x * 128, m0 = my * 128;
    const int tid = threadIdx.x;
    const int w = tid >> 6, lane = tid & 63, q = lane >> 4, li = lane & 15;
    const int wr = w >> 1, wc = w & 1;

    const int srow = tid >> 3;
    const int cg = (tid & 7) ^ (srow & 7);
    const int ldsbase = ((tid >> 6) * 8) * 64;

    f32x4 acc[4][4];
    #pragma unroll
    for (int i = 0; i < 4; i++)
        #pragma unroll
        for (int j = 0; j < 4; j++) acc[i][j] = (f32x4){0.f, 0.f, 0.f, 0.f};

    #pragma unroll
    for (int kt = 0; kt < 128; kt += 64) {
        const u16* Ab = A + (long)m0 * 128 + kt + cg * 8;
        const u16* Bb = B + (long)n0 * 128 + kt + cg * 8;
        #pragma unroll
        for (int c = 0; c < 4; c++) {
            gload_lds16(Ab + (long)(c * 32 + srow) * 128, &As[ldsbase + c * 32 * 64]);
            gload_lds16(Bb + (long)(c * 32 + srow) * 128, &Bs[ldsbase + c * 32 * 64]);
        }
        __syncthreads();
        #pragma unroll
        for (int s = 0; s < 2; s++) {
            const int cp = ((s * 4 + q) ^ (li & 7)) * 8;
            bf16x8 av[4], bv[4];
            #pragma unroll
            for (int i = 0; i < 4; i++)
                av[i] = *(bf16x8*)&As[(wr * 64 + i * 16 + li) * 64 + cp];
            #pragma unroll
            for (int j = 0; j < 4; j++)
                bv[j] = *(bf16x8*)&Bs[(wc * 64 + j * 16 + li) * 64 + cp];
            #pragma unroll
            for (int i = 0; i < 4; i++)
                #pragma unroll
                for (int j = 0; j < 4; j++)
                    acc[i][j] = mfma16(av[i], bv[j], acc[i][j]);
        }
        __syncthreads();
    }

    const int Lm = (1 << logL) - 1;
    #pragma unroll
    for (int i = 0; i < 4; i++) {
        #pragma unroll
        for (int j = 0; j < 4; j++) {
            const int col = n0 + wc * 64 + j * 16 + li;
            const float bvs = bias[col];
            if (mode == 3) {
                const int row0 = m0 + wr * 64 + i * 16 + q * 4;
                long base = ((long)(((row0 >> logL) * 8 + (col >> 7)) * 128
                            + (col & 127)) << logL) + (row0 & Lm);
                u16x4 o;
                #pragma unroll
                for (int r = 0; r < 4; r++)
                    o[r] = f2u(fmaxf(acc[i][j][r] + bvs, 0.f));
                *(u16x4*)(Out + base) = o;
            } else {
                #pragma unroll
                for (int r = 0; r < 4; r++) {
                    const int row = m0 + wr * 64 + i * 16 + q * 4 + r;
                    long addr = ((long)((row >> logL) * 8 + (col >> 7)) << (logL + 7))
                              + ((long)(row & Lm) << 7) + (col & 127);
                    Out[addr] = f2u(fmaxf(acc[i][j][r] + bvs, 0.f));
                }
            }
        }
    }
}

// ---------------------------------------------------------------------------
// Merged AV: blocks [0,128): lig AV (per bh: C[256 l][128 d] = att @ p2^T,
// both k-minor via global_load_lds). blocks [128,640): prot AV (per
// (bh, p-quarter): C[256 p][128 d] = att^T @ l2) with CONFLICT-FREE two-stage
// transpose: stage1 gload att tile -> T[64 l][256 p] (HW-contiguous, no
// conflicts); stage2 per-wave LDS transpose T -> XOR-swizzled As[256 p][64 l]
// (reads: lanes along p = conflict-free; writes: 4 b128/thread/kt);
// stage3 MFMA reads XOR pattern (proven clean). B via gload+XOR.
// 512 threads = 8 waves (4 row-quadrants x 2 col-halves).
// ---------------------------------------------------------------------------
__global__ __launch_bounds__(512)
void av_kernel(const u16* __restrict__ att, const u16* __restrict__ p2t,
               const u16* __restrict__ l2t,
               u16* __restrict__ lig3, u16* __restrict__ prot3)
{
    __shared__ __align__(16) u16 As[256 * 64];   // 32 KB
    __shared__ __align__(16) u16 Bs[128 * 64];   // 16 KB
    __shared__ __align__(16) u16 T[64 * 256];    // 32 KB (prot stage-1 tile)
    const int bid = blockIdx.x;
    const int tid = threadIdx.x;
    const int w = tid >> 6, lane = tid & 63, q = lane >> 4, li = lane & 15;
    const int wr = w >> 1, wc = w & 1;     // wr 0..3 (rows), wc 0..1 (cols)

    f32x4 acc[4][4];
    #pragma unroll
    for (int i = 0; i < 4; i++)
        #pragma unroll
        for (int j = 0; j < 4; j++) acc[i][j] = (f32x4){0.f, 0.f, 0.f, 0.f};

    if (bid < 128) {
        // ---------------- lig AV ----------------
        const int bh = bid;
        const u16* A = att + (long)bh * 262144;   // [256 l][1024 p]
        const u16* B = p2t + (long)bh * 131072;   // [128 d][1024 p]
        const int srow = tid >> 3;                // 0..63
        const int cg = (tid & 7) ^ (srow & 7);
        const int ldsbase = ((tid >> 6) * 8) * 64;

        for (int kt = 0; kt < 1024; kt += 64) {
            const u16* Ab = A + kt + cg * 8;
            const u16* Bb = B + kt + cg * 8;
            #pragma unroll
            for (int c = 0; c < 4; c++)
                gload_lds16(Ab + (long)(c * 64 + srow) * 1024,
                            &As[ldsbase + c * 64 * 64]);
            #pragma unroll
            for (int c = 0; c < 2; c++)
                gload_lds16(Bb + (long)(c * 64 + srow) * 1024,
                            &Bs[ldsbase + c * 64 * 64]);
            __syncthreads();
            #pragma unroll
            for (int s = 0; s < 2; s++) {
                const int cp = ((s * 4 + q) ^ (li & 7)) * 8;
                bf16x8 av[4], bv[4];
                #pragma unroll
                for (int i = 0; i < 4; i++)
                    av[i] = *(bf16x8*)&As[(wr * 64 + i * 16 + li) * 64 + cp];
                #pragma unroll
                for (int j = 0; j < 4; j++)
                    bv[j] = *(bf16x8*)&Bs[(wc * 64 + j * 16 + li) * 64 + cp];
                #pragma unroll
                for (int i = 0; i < 4; i++)
                    #pragma unroll
                    for (int j = 0; j < 4; j++)
                        acc[i][j] = mfma16(av[i], bv[j], acc[i][j]);
            }
            __syncthreads();
        }

        const long obase = ((long)(bh >> 3) * 256) * 1024 + (long)(bh & 7) * 128;
        #pragma unroll
        for (int i = 0; i < 4; i++)
            #pragma unroll
            for (int j = 0; j < 4; j++) {
                const int col = wc * 64 + j * 16 + li;
                #pragma unroll
                for (int r = 0; r < 4; r++) {
                    const int row = wr * 64 + i * 16 + q * 4 + r;
                    lig3[obase + (long)row * 1024 + col] = f2u(acc[i][j][r]);
                }
            }
    } else {
        // ---------------- prot AV ----------------
        const int pb = bid - 128;
        const int bh = pb >> 2;
        const int m0 = (pb & 3) * 256;            // p-offset
        const u16* A = att + (long)bh * 262144;   // [256 l][1024 p]
        const u16* B = l2t + (long)bh * 32768;    // [128 d][256 l]
        const int w6 = tid >> 6;                  // wave id 0..7
        const int i5 = (tid >> 5) & 1;
        const int srow = tid >> 3;                // 0..63 (B staging)
        const int cg = (tid & 7) ^ (srow & 7);
        const int bldsbase = w6 * 8 * 64;

        for (int kt = 0; kt < 256; kt += 64) {
            // stage 1: gload att rows [kt, kt+64) x p [m0, m0+256) -> T[l][p]
            // wave w covers T rows w*8 .. w*8+7 (contiguous flat segments)
            #pragma unroll
            for (int c = 0; c < 4; c++) {
                gload_lds16(A + (long)(kt + w6 * 8 + c * 2 + i5) * 1024
                              + m0 + (tid & 31) * 8,
                            &T[w6 * 2048 + c * 512]);
            }
            // B staging: l2t k-minor via gload + XOR
            #pragma unroll
            for (int c = 0; c < 2; c++)
                gload_lds16(B + (long)(c * 64 + srow) * 256 + kt + cg * 8,
                            &Bs[bldsbase + c * 64 * 64]);
            __syncthreads();

            // stage 2: transpose T -> As (XOR chunk swizzle).
            // wave w owns l-chunk w; lanes along p (conflict-free reads).
            #pragma unroll
            for (int pass = 0; pass < 4; pass++) {
                const int p = pass * 64 + (tid & 63);
                union { u16 e[8]; u32x4 v; } tmp;
                #pragma unroll
                for (int e = 0; e < 8; e++)
                    tmp.e[e] = T[(w6 * 8 + e) * 256 + p];
                *(u32x4*)&As[p * 64 + ((w6 ^ (p & 7)) * 8)] = tmp.v;
            }
            __syncthreads();

            // stage 3: MFMA (XOR reads, proven conflict-free)
            #pragma unroll
            for (int s = 0; s < 2; s++) {
                const int cp = ((s * 4 + q) ^ (li & 7)) * 8;
                bf16x8 av[4], bv[4];
                #pragma unroll
                for (int i = 0; i < 4; i++)
                    av[i] = *(bf16x8*)&As[(wr * 64 + i * 16 + li) * 64 + cp];
                #pragma unroll
                for (int j = 0; j < 4; j++)
                    bv[j] = *(bf16x8*)&Bs[(wc * 64 + j * 16 + li) * 64 + cp];
                #pragma unroll
                for (int i = 0; i < 4; i++)
                    #pragma unroll
                    for (int j = 0; j < 4; j++)
                        acc[i][j] = mfma16(av[i], bv[j], acc[i][j]);
            }
            __syncthreads();
        }

        const long obase = ((long)(bh >> 3) * 1024 + m0) * 1024 + (long)(bh & 7) * 128;
        #pragma unroll
        for (int i = 0; i < 4; i++)
            #pragma unroll
            for (int j = 0; j < 4; j++) {
                const int col = wc * 64 + j * 16 + li;
                #pragma unroll
                for (int r = 0; r < 4; r++) {
                    const int row = wr * 64 + i * 16 + q * 4 + r;
                    prot3[obase + (long)row * 1024 + col] = f2u(acc[i][j][r]);
                }
            }
    }
}

// ---------------------------------------------------------------------------
// Merged finals: out = relu([X, resid] @ Wst^T + bc), K = 1024+128 (STACK).
// grid (1, 160): y<32 lig -> out0, else prot -> out1. fp32 out, ldOut=128.
// ---------------------------------------------------------------------------
__global__ __launch_bounds__(256)
void finals_kernel(const u16* __restrict__ lig3, const u16* __restrict__ ligb,
                   const u16* __restrict__ WstL, const float* __restrict__ bcL,
                   float* __restrict__ out0,
                   const u16* __restrict__ prot3, const u16* __restrict__ protb,
                   const u16* __restrict__ WstP, const float* __restrict__ bcP,
                   float* __restrict__ out1)
{
    __shared__ __align__(16) u16 As[128 * 64];
    __shared__ __align__(16) u16 Bs[128 * 64];
    const int y = blockIdx.y;
    const u16 *A, *A2, *B; const float* bias; float* Out; int my;
    if (y < 32) { A = lig3;  A2 = ligb;  B = WstL; bias = bcL; Out = out0; my = y; }
    else        { A = prot3; A2 = protb; B = WstP; bias = bcP; Out = out1; my = y - 32; }
    const int m0 = my * 128;
    const int tid = threadIdx.x;
    const int w = tid >> 6, lane = tid & 63, q = lane >> 4, li = lane & 15;
    const int wr = w >> 1, wc = w & 1;

    const int srow = tid >> 3;
    const int cg = (tid & 7) ^ (srow & 7);
    const int ldsbase = ((tid >> 6) * 8) * 64;

    f32x4 acc[4][4];
    #pragma unroll
    for (int i = 0; i < 4; i++)
        #pragma unroll
        for (int j = 0; j < 4; j++) acc[i][j] = (f32x4){0.f, 0.f, 0.f, 0.f};

    for (int kt = 0; kt < 1152; kt += 64) {
        const u16* Abase; long lda; int ktA;
        if (kt >= 1024) { Abase = A2; lda = 128; ktA = kt - 1024; }
        else            { Abase = A;  lda = 1024; ktA = kt; }
        const u16* Ab = Abase + (long)m0 * lda + ktA + cg * 8;
        const u16* Bb = B + kt + cg * 8;          // n0 = 0, ld 1152
        #pragma unroll
        for (int c = 0; c < 4; c++) {
            gload_lds16(Ab + (long)(c * 32 + srow) * lda,  &As[ldsbase + c * 32 * 64]);
            gload_lds16(Bb + (long)(c * 32 + srow) * 1152, &Bs[ldsbase + c * 32 * 64]);
        }
        __syncthreads();
        #pragma unroll
        for (int s = 0; s < 2; s++) {
            const int cp = ((s * 4 + q) ^ (li & 7)) * 8;
            bf16x8 av[4], bv[4];
            #pragma unroll
            for (int i = 0; i < 4; i++)
                av[i] = *(bf16x8*)&As[(wr * 64 + i * 16 + li) * 64 + cp];
            #pragma unroll
            for (int j = 0; j < 4; j++)
                bv[j] = *(bf16x8*)&Bs[(wc * 64 + j * 16 + li) * 64 + cp];
            #pragma unroll
            for (int i = 0; i < 4; i++)
                #pragma unroll
                for (int j = 0; j < 4; j++)
                    acc[i][j] = mfma16(av[i], bv[j], acc[i][j]);
        }
        __syncthreads();
    }

    #pragma unroll
    for (int i = 0; i < 4; i++)
        #pragma unroll
        for (int j = 0; j < 4; j++) {
            const int col = wc * 64 + j * 16 + li;
            const float bvs = bias[col];
            #pragma unroll
            for (int r = 0; r < 4; r++) {
                const int row = m0 + wr * 64 + i * 16 + q * 4 + r;
                Out[(long)row * 128 + col] = fmaxf(acc[i][j][r] + bvs, 0.f);
            }
        }
}

// ---------------------------------------------------------------------------
// Attention v2: per (m-tile 16, bh).
// Phase 1 (MFMA layout): S'[16 l][1024 p] = (l1 . p1)*rscale -> bf16 LDS tile,
//   XOR-swizzled (phys col = col ^ ((row>>2)<<4)) so both the scalar u16
//   stores (q-groups spread 8 banks apart) and the later b128 row reads are
//   conflict-free. 32 KB LDS exactly -> 5 blocks/CU.
// Phases 2-4 (row layout: row = tid>>4, 16 lanes own a full 1024-wide row):
//   2: s *= inter (bf16x8 coalesced global), write product back, row max via
//      4 shfl_xor (row never crosses a 16-lane group -> no LDS reduction).
//   3: sum of exp (shfl reduce).
//   4: recompute exp, scale by 1/Z, store att as 16B vectors.
// Register state ~8 f32/lane (was 64 -> AGPR spill churn + 42% occupancy).
// ---------------------------------------------------------------------------
__global__ __launch_bounds__(256, 5)
void attn_kernel(const u16* __restrict__ l1, const u16* __restrict__ p1,
                 const u16* __restrict__ interb, u16* __restrict__ att)
{
    __shared__ __align__(16) u16 S[16 * 1024];   // 32 KB, swizzled bf16 scores
    const int bh = blockIdx.y;
    const int b  = bh >> 3;
    const int m0 = blockIdx.x * 16;
    const int tid = threadIdx.x;
    const float rscale = 0.08838834764831845f; // 1/sqrt(128)

    // ---- phase 1: raw scores into LDS ----
    {
        const int w = tid >> 6, lane = tid & 63, q = lane >> 4, li = lane & 15;
        bf16x8 af[4];
        const u16* lp = l1 + ((long)bh * 256 + m0 + li) * 128 + q * 8;
        #pragma unroll
        for (int s = 0; s < 4; s++) af[s] = *(const bf16x8*)(lp + s * 32);
        const int sw = q << 4;
        #pragma unroll 4
        for (int t = 0; t < 16; t++) {
            const int n0 = w * 256 + t * 16;
            const u16* bp = p1 + ((long)bh * 1024 + n0 + li) * 128 + q * 8;
            f32x4 acc = (f32x4){0.f, 0.f, 0.f, 0.f};
            #pragma unroll
            for (int s = 0; s < 4; s++)
                acc = mfma16(af[s], *(const bf16x8*)(bp + s * 32), acc);
            #pragma unroll
            for (int r = 0; r < 4; r++) {
                const int row = q * 4 + r;
                S[(row << 10) + ((n0 + li) ^ sw)] = f2u(acc[r] * rscale);
            }
        }
    }
    __syncthreads();

    // ---- phases 2-4: each row owned by one 16-lane group ----
    const int row = tid >> 4;          // 0..15
    const int lj  = tid & 15;          // column chunk within row
    const int l   = m0 + row;
    const int sw2 = (row >> 2) << 4;
    const u16* ib = interb + ((long)b * 256 + l) * 1024;

    // phase 2: multiply by inter (coalesced bf16x8), write back, row max
    float mx = -1e30f;
    #pragma unroll
    for (int blk = 0; blk < 8; blk++) {
        const int c = blk * 128 + lj * 8;
        u16* sp = &S[(row << 10) + (c ^ sw2)];
        u16x8 s8 = *(u16x8*)sp;
        u16x8 i8 = *(const u16x8*)(ib + c);
        u16x8 o8;
        #pragma unroll
        for (int e = 0; e < 8; e++) {
            float v = u2f(s8[e]) * u2f(i8[e]);
            mx = fmaxf(mx, v);
            o8[e] = f2u(v);
        }
        *(u16x8*)sp = o8;
    }
    #pragma unroll
    for (int d = 1; d < 16; d <<= 1) mx = fmaxf(mx, __shfl_xor(mx, d, 64));

    // phase 3: sum of exp
    float z = 0.f;
    #pragma unroll
    for (int blk = 0; blk < 8; blk++) {
        const int c = blk * 128 + lj * 8;
        u16x8 p8 = *(u16x8*)&S[(row << 10) + (c ^ sw2)];
        #pragma unroll
        for (int e = 0; e < 8; e++) z += __expf(u2f(p8[e]) - mx);
    }
    #pragma unroll
    for (int d = 1; d < 16; d <<= 1) z += __shfl_xor(z, d, 64);
    const float inv = 1.f / z;

    // phase 4: normalize + vectorized store
    u16* op = att + ((long)bh * 256 + l) * 1024;
    #pragma unroll
    for (int blk = 0; blk < 8; blk++) {
        const int c = blk * 128 + lj * 8;
        u16x8 p8 = *(u16x8*)&S[(row << 10) + (c ^ sw2)];
        u16x8 o8;
        #pragma unroll
        for (int e = 0; e < 8; e++)
            o8[e] = f2u(__expf(u2f(p8[e]) - mx) * inv);
        *(u16x8*)(op + c) = o8;
    }
}

// ---------------------------------------------------------------------------
// Fused 8-way transpose + fp32->bf16 convert for weights: dst[C,R] = bf16(src^T)
// ---------------------------------------------------------------------------
struct TPF { const float* src; u16* dst; int R; int C; };
struct TPF8 { TPF t[8]; };

__global__ __launch_bounds__(256)
void cvtw_kernel(TPF8 args)
{
    TPF tp = args.t[blockIdx.z];
    const int c0 = blockIdx.x * 32, r0 = blockIdx.y * 32;
    if (c0 >= tp.C || r0 >= tp.R) return;
    __shared__ u16 tile[32][33];
    const int tx = threadIdx.x & 31, ty = threadIdx.x >> 5;
    #pragma unroll
    for (int i = 0; i < 4; i++)
        tile[ty + i * 8][tx] = f2u(tp.src[(long)(r0 + ty + i * 8) * tp.C + c0 + tx]);
    __syncthreads();
    #pragma unroll
    for (int i = 0; i < 4; i++)
        tp.dst[(long)(c0 + ty + i * 8) * tp.R + r0 + tx] = tile[tx][ty + i * 8];
}

// ---------------------------------------------------------------------------
// Weight-combine: Wst[n][0:1024] = Wout_t[n][0:128] @ Wmid_t; tail = resid W;
// bc[n] = bout[n] + bmid . Wout_t[n][0:128].
// ---------------------------------------------------------------------------
__global__ __launch_bounds__(256)
void wcomb_kernel(const u16* __restrict__ Wm0, const u16* __restrict__ Wo0,
                  const float* __restrict__ bm0, const float* __restrict__ bo0,
                  u16* __restrict__ Wst0, float* __restrict__ bc0,
                  const u16* __restrict__ Wm1, const u16* __restrict__ Wo1,
                  const float* __restrict__ bm1, const float* __restrict__ bo1,
                  u16* __restrict__ Wst1, float* __restrict__ bc1)
{
    const int zz = blockIdx.y;
    const u16* Wm = zz ? Wm1 : Wm0;
    const u16* Wo = zz ? Wo1 : Wo0;
    const float* bmid = zz ? bm1 : bm0;
    const float* bout = zz ? bo1 : bo0;
    u16* Wst = zz ? Wst1 : Wst0;
    float* bc = zz ? bc1 : bc0;
    const int n = blockIdx.x;
    const int tid = threadIdx.x;
    __shared__ float wrow[128];
    if (tid < 128) wrow[tid] = u2f(Wo[n * 256 + tid]);
    __syncthreads();
    for (int k = tid; k < 1024; k += 256) {
        float acc = 0.f;
        #pragma unroll 4
        for (int j = 0; j < 128; j++) acc += wrow[j] * u2f(Wm[(long)j * 1024 + k]);
        Wst[(long)n * 1152 + k] = f2u(acc);
    }
    if (tid < 128) Wst[(long)n * 1152 + 1024 + tid] = Wo[n * 256 + 128 + tid];
    if (tid == 0) {
        float acc = bout[n];
        for (int j = 0; j < 128; j++) acc += bmid[j] * wrow[j];
        bc[n] = acc;
    }
}

// ---------------------------------------------------------------------------
// fp32 -> bf16 converts: z=0 ligand, z=1 prot, z=2 inter
// ---------------------------------------------------------------------------
__global__ __launch_bounds__(256)
void cvt3_kernel(const float* __restrict__ a, u16* __restrict__ da, int na,
                 const float* __restrict__ b, u16* __restrict__ db, int nb,
                 const float* __restrict__ c, u16* __restrict__ dc, int nc)
{
    const int zz = blockIdx.y;
    const float* s = zz == 0 ? a : (zz == 1 ? b : c);
    u16* d = zz == 0 ? da : (zz == 1 ? db : dc);
    const int n = zz == 0 ? na : (zz == 1 ? nb : nc);
    const int i = (blockIdx.x * 256 + threadIdx.x) * 4;
    if (i >= n) return;
    const float4 v = *(const float4*)(s + i);
    u16x4 o;
    o.x = f2u(v.x); o.y = f2u(v.y); o.z = f2u(v.z); o.w = f2u(v.w);
    *(u16x4*)(d + i) = o;
}

// ---------------------------------------------------------------------------
extern "C" void kernel_launch(void* const* d_in, const int* in_sizes, int n_in,
                              void* d_out, int out_size, void* d_ws, size_t ws_size,
                              hipStream_t stream)
{
    (void)in_sizes; (void)n_in; (void)out_size; (void)ws_size;
    const float* ligand = (const float*)d_in[0];
    const float* prot   = (const float*)d_in[1];
    const float* inter  = (const float*)d_in[2];
    const float* Wl1 = (const float*)d_in[3];  const float* bl1 = (const float*)d_in[4];
    const float* Wl2 = (const float*)d_in[5];  const float* bl2 = (const float*)d_in[6];
    const float* Wp1 = (const float*)d_in[7];  const float* bp1 = (const float*)d_in[8];
    const float* Wp2 = (const float*)d_in[9];  const float* bp2 = (const float*)d_in[10];
    const float* W11 = (const float*)d_in[11]; const float* b11 = (const float*)d_in[12];
    const float* W12 = (const float*)d_in[13]; const float* b12 = (const float*)d_in[14];
    const float* W21 = (const float*)d_in[15]; const float* b21 = (const float*)d_in[16];
    const float* W22 = (const float*)d_in[17]; const float* b22 = (const float*)d_in[18];

    float* out0 = (float*)d_out;                    // [16,256,128]
    float* out1 = out0 + (size_t)16 * 256 * 128;    // [16,1024,128]

    u16* ws = (u16*)d_ws;
    size_t off = 0;
    auto alloc = [&](size_t n) { u16* p = ws + off; off += n; return p; };
    u16* ligb  = alloc(524288);    // bf16 ligand [4096,128]
    u16* protb = alloc(2097152);   // bf16 prot  [16384,128]
    u16* l1v   = alloc(4194304);   // [16,8,256,128]
    u16* l2t   = alloc(4194304);   // [16,8,128,256]  (head-T)
    u16* p1v   = alloc(16777216);  // [16,8,1024,128]
    u16* p2t   = alloc(16777216);  // [16,8,128,1024] (head-T)
    u16* attv  = alloc(33554432);  // [16,8,256,1024]
    u16* lig3  = alloc(4194304);   // [16,256,1024]
    u16* prot3 = alloc(16777216);  // [16,1024,1024]
    u16* Wl1t  = alloc(131072);    // [1024,128]
    u16* Wl2t  = alloc(131072);
    u16* Wp1t  = alloc(131072);
    u16* Wp2t  = alloc(131072);
    u16* W11t  = alloc(131072);    // [128,1024] = W11^T
    u16* W21t  = alloc(131072);    // [128,1024] = W21^T
    u16* W12t  = alloc(32768);     // [128,256]  = W12^T
    u16* W22t  = alloc(32768);     // [128,256]  = W22^T
    u16* WstL  = alloc(147456);    // [128,1152] combined lig weight
    u16* WstP  = alloc(147456);    // [128,1152] combined prot weight
    float* bcL = (float*)alloc(256);  // [128] f32
    float* bcP = (float*)alloc(256);  // [128] f32

    // interb aliases lig3: interb is consumed by attn_kernel, which completes
    // before av_kernel writes lig3 (stream-ordered). Sizes match exactly
    // (16*256*1024 u16).
    u16* interb = lig3;

    // input conversion (ligand, prot, inter) -> bf16
    cvt3_kernel<<<dim3(4096, 3), 256, 0, stream>>>(
        ligand, ligb, 524288, prot, protb, 2097152, inter, interb, 4194304);

    TPF8 tp;
    tp.t[0] = {Wl1, Wl1t, 128, 1024};
    tp.t[1] = {Wl2, Wl2t, 128, 1024};
    tp.t[2] = {Wp1, Wp1t, 128, 1024};
    tp.t[3] = {Wp2, Wp2t, 128, 1024};
    tp.t[4] = {W11, W11t, 1024, 128};
    tp.t[5] = {W21, W21t, 1024, 128};
    tp.t[6] = {W12, W12t, 256, 128};
    tp.t[7] = {W22, W22t, 256, 128};
    cvtw_kernel<<<dim3(32, 32, 8), 256, 0, stream>>>(tp);

    // combine W11@W12top / W21@W22top + residual halves + biases
    wcomb_kernel<<<dim3(128, 2), 256, 0, stream>>>(
        W11t, W12t, b11, b12, WstL, bcL,
        W21t, W22t, b21, b22, WstP, bcP);

    // all four projections in one dispatch
    proj_kernel<<<dim3(8, 320), 256, 0, stream>>>(
        ligb, protb, Wl1t, Wl2t, Wp1t, Wp2t,
        bl1, bl2, bp1, bp2, l1v, l2t, p1v, p2t);

    // attention scores + softmax (bf16 inter, LDS score tile)
    attn_kernel<<<dim3(16, 128), 256, 0, stream>>>(l1v, p1v, interb, attv);

    // both AV GEMMs in one dispatch (conflict-free prot transpose staging)
    av_kernel<<<dim3(640), 512, 0, stream>>>(attv, p2t, l2t, lig3, prot3);

    // both fused finals in one dispatch
    finals_kernel<<<dim3(1, 160), 256, 0, stream>>>(
        lig3, ligb, WstL, bcL, out0,
        prot3, protb, WstP, bcP, out1);
}

// Round 2
// 282.513 us; speedup vs baseline: 1.1651x; 1.1330x over previous
//
#include <hip/hip_runtime.h>
#include <hip/hip_bf16.h>

typedef unsigned short u16;
typedef __attribute__((ext_vector_type(4))) float f32x4;
typedef __attribute__((ext_vector_type(4))) unsigned int u32x4;
typedef __attribute__((ext_vector_type(4))) unsigned short u16x4;
typedef __attribute__((ext_vector_type(8))) unsigned short u16x8;
typedef __attribute__((ext_vector_type(8))) __bf16 bf16x8;

__device__ inline float u2f(u16 u) {
    union { unsigned int i; float f; } x; x.i = ((unsigned int)u) << 16; return x.f;
}
__device__ inline u16 f2u(float f) {
    __hip_bfloat16 b = __float2bfloat16(f);
    return *reinterpret_cast<u16*>(&b);
}
__device__ inline f32x4 mfma16(bf16x8 a, bf16x8 b, f32x4 c) {
    return __builtin_amdgcn_mfma_f32_16x16x32_bf16(a, b, c, 0, 0, 0);
}
__device__ inline void gload_lds16(const u16* g, u16* l) {
    __builtin_amdgcn_global_load_lds(
        (const __attribute__((address_space(1))) unsigned int*)g,
        (__attribute__((address_space(3))) unsigned int*)l, 16, 0, 0);
}

// ---------------------------------------------------------------------------
// Merged projection GEMMs: one dispatch for all four x@W+b (relu) projections.
// grid (8, 320): y<32 lig->l1v(mode1), y<64 lig->l2t(mode3),
// y<192 prot->p1v(mode1), else prot->p2t(mode3). 128x128 tile, K=128.
// ---------------------------------------------------------------------------
__global__ __launch_bounds__(256)
void proj_kernel(const u16* __restrict__ ligb, const u16* __restrict__ protb,
                 const u16* __restrict__ Wl1t, const u16* __restrict__ Wl2t,
                 const u16* __restrict__ Wp1t, const u16* __restrict__ Wp2t,
                 const float* __restrict__ bl1, const float* __restrict__ bl2,
                 const float* __restrict__ bp1, const float* __restrict__ bp2,
                 u16* __restrict__ l1v, u16* __restrict__ l2tv,
                 u16* __restrict__ p1v, u16* __restrict__ p2tv)
{
    __shared__ __align__(16) u16 As[128 * 64];
    __shared__ __align__(16) u16 Bs[128 * 64];
    const int y = blockIdx.y;
    const u16* A; const u16* B; const float* bias; u16* Out;
    int mode, logL, my;
    if (y < 32)       { A = ligb;  B = Wl1t; bias = bl1; Out = l1v;  mode = 1; logL = 8;  my = y; }
    else if (y < 64)  { A = ligb;  B = Wl2t; bias = bl2; Out = l2tv; mode = 3; logL = 8;  my = y - 32; }
    else if (y < 192) { A = protb; B = Wp1t; bias = bp1; Out = p1v;  mode = 1; logL = 10; my = y - 64; }
    else              { A = protb; B = Wp2t; bias = bp2; Out = p2tv; mode = 3; logL = 10; my = y - 192; }
    const int n0 = blockIdx.x * 128, m0 = my * 128;
    const int tid = threadIdx.x;
    const int w = tid >> 6, lane = tid & 63, q = lane >> 4, li = lane & 15;
    const int wr = w >> 1, wc = w & 1;

    const int srow = tid >> 3;
    const int cg = (tid & 7) ^ (srow & 7);
    const int ldsbase = ((tid >> 6) * 8) * 64;

    f32x4 acc[4][4];
    #pragma unroll
    for (int i = 0; i < 4; i++)
        #pragma unroll
        for (int j = 0; j < 4; j++) acc[i][j] = (f32x4){0.f, 0.f, 0.f, 0.f};

    #pragma unroll
    for (int kt = 0; kt < 128; kt += 64) {
        const u16* Ab = A + (long)m0 * 128 + kt + cg * 8;
        const u16* Bb = B + (long)n0 * 128 + kt + cg * 8;
        #pragma unroll
        for (int c = 0; c < 4; c++) {
            gload_lds16(Ab + (long)(c * 32 + srow) * 128, &As[ldsbase + c * 32 * 64]);
            gload_lds16(Bb + (long)(c * 32 + srow) * 128, &Bs[ldsbase + c * 32 * 64]);
        }
        __syncthreads();
        #pragma unroll
        for (int s = 0; s < 2; s++) {
            const int cp = ((s * 4 + q) ^ (li & 7)) * 8;
            bf16x8 av[4], bv[4];
            #pragma unroll
            for (int i = 0; i < 4; i++)
                av[i] = *(bf16x8*)&As[(wr * 64 + i * 16 + li) * 64 + cp];
            #pragma unroll
            for (int j = 0; j < 4; j++)
                bv[j] = *(bf16x8*)&Bs[(wc * 64 + j * 16 + li) * 64 + cp];
            #pragma unroll
            for (int i = 0; i < 4; i++)
                #pragma unroll
                for (int j = 0; j < 4; j++)
                    acc[i][j] = mfma16(av[i], bv[j], acc[i][j]);
        }
        __syncthreads();
    }

    const int Lm = (1 << logL) - 1;
    #pragma unroll
    for (int i = 0; i < 4; i++) {
        #pragma unroll
        for (int j = 0; j < 4; j++) {
            const int col = n0 + wc * 64 + j * 16 + li;
            const float bvs = bias[col];
            if (mode == 3) {
                const int row0 = m0 + wr * 64 + i * 16 + q * 4;
                long base = ((long)(((row0 >> logL) * 8 + (col >> 7)) * 128
                            + (col & 127)) << logL) + (row0 & Lm);
                u16x4 o;
                #pragma unroll
                for (int r = 0; r < 4; r++)
                    o[r] = f2u(fmaxf(acc[i][j][r] + bvs, 0.f));
                *(u16x4*)(Out + base) = o;
            } else {
                #pragma unroll
                for (int r = 0; r < 4; r++) {
                    const int row = m0 + wr * 64 + i * 16 + q * 4 + r;
                    long addr = ((long)((row >> logL) * 8 + (col >> 7)) << (logL + 7))
                              + ((long)(row & Lm) << 7) + (col & 127);
                    Out[addr] = f2u(fmaxf(acc[i][j][r] + bvs, 0.f));
                }
            }
        }
    }
}

// ---------------------------------------------------------------------------
// Merged AV: blocks [0,128): lig AV (per bh: C[256 l][128 d] = att @ p2^T,
// both k-minor via global_load_lds). blocks [128,640): prot AV (per
// (bh, p-quarter): C[256 p][128 d] = att^T @ l2) with CONFLICT-FREE two-stage
// transpose: stage1 gload att tile -> T[64 l][256 p] (HW-contiguous, no
// conflicts); stage2 per-wave LDS transpose T -> XOR-swizzled As[256 p][64 l]
// (reads: lanes along p = conflict-free; writes: 4 b128/thread/kt);
// stage3 MFMA reads XOR pattern (proven clean). B via gload+XOR.
// 512 threads = 8 waves (4 row-quadrants x 2 col-halves).
// ---------------------------------------------------------------------------
__global__ __launch_bounds__(512)
void av_kernel(const u16* __restrict__ att, const u16* __restrict__ p2t,
               const u16* __restrict__ l2t,
               u16* __restrict__ lig3, u16* __restrict__ prot3)
{
    __shared__ __align__(16) u16 As[256 * 64];   // 32 KB
    __shared__ __align__(16) u16 Bs[128 * 64];   // 16 KB
    __shared__ __align__(16) u16 T[64 * 256];    // 32 KB (prot stage-1 tile)
    const int bid = blockIdx.x;
    const int tid = threadIdx.x;
    const int w = tid >> 6, lane = tid & 63, q = lane >> 4, li = lane & 15;
    const int wr = w >> 1, wc = w & 1;     // wr 0..3 (rows), wc 0..1 (cols)

    f32x4 acc[4][4];
    #pragma unroll
    for (int i = 0; i < 4; i++)
        #pragma unroll
        for (int j = 0; j < 4; j++) acc[i][j] = (f32x4){0.f, 0.f, 0.f, 0.f};

    if (bid < 128) {
        // ---------------- lig AV ----------------
        const int bh = bid;
        const u16* A = att + (long)bh * 262144;   // [256 l][1024 p]
        const u16* B = p2t + (long)bh * 131072;   // [128 d][1024 p]
        const int srow = tid >> 3;                // 0..63
        const int cg = (tid & 7) ^ (srow & 7);
        const int ldsbase = ((tid >> 6) * 8) * 64;

        for (int kt = 0; kt < 1024; kt += 64) {
            const u16* Ab = A + kt + cg * 8;
            const u16* Bb = B + kt + cg * 8;
            #pragma unroll
            for (int c = 0; c < 4; c++)
                gload_lds16(Ab + (long)(c * 64 + srow) * 1024,
                            &As[ldsbase + c * 64 * 64]);
            #pragma unroll
            for (int c = 0; c < 2; c++)
                gload_lds16(Bb + (long)(c * 64 + srow) * 1024,
                            &Bs[ldsbase + c * 64 * 64]);
            __syncthreads();
            #pragma unroll
            for (int s = 0; s < 2; s++) {
                const int cp = ((s * 4 + q) ^ (li & 7)) * 8;
                bf16x8 av[4], bv[4];
                #pragma unroll
                for (int i = 0; i < 4; i++)
                    av[i] = *(bf16x8*)&As[(wr * 64 + i * 16 + li) * 64 + cp];
                #pragma unroll
                for (int j = 0; j < 4; j++)
                    bv[j] = *(bf16x8*)&Bs[(wc * 64 + j * 16 + li) * 64 + cp];
                #pragma unroll
                for (int i = 0; i < 4; i++)
                    #pragma unroll
                    for (int j = 0; j < 4; j++)
                        acc[i][j] = mfma16(av[i], bv[j], acc[i][j]);
            }
            __syncthreads();
        }

        const long obase = ((long)(bh >> 3) * 256) * 1024 + (long)(bh & 7) * 128;
        #pragma unroll
        for (int i = 0; i < 4; i++)
            #pragma unroll
            for (int j = 0; j < 4; j++) {
                const int col = wc * 64 + j * 16 + li;
                #pragma unroll
                for (int r = 0; r < 4; r++) {
                    const int row = wr * 64 + i * 16 + q * 4 + r;
                    lig3[obase + (long)row * 1024 + col] = f2u(acc[i][j][r]);
                }
            }
    } else {
        // ---------------- prot AV ----------------
        const int pb = bid - 128;
        const int bh = pb >> 2;
        const int m0 = (pb & 3) * 256;            // p-offset
        const u16* A = att + (long)bh * 262144;   // [256 l][1024 p]
        const u16* B = l2t + (long)bh * 32768;    // [128 d][256 l]
        const int w6 = tid >> 6;                  // wave id 0..7
        const int i5 = (tid >> 5) & 1;
        const int srow = tid >> 3;                // 0..63 (B staging)
        const int cg = (tid & 7) ^ (srow & 7);
        const int bldsbase = w6 * 8 * 64;

        for (int kt = 0; kt < 256; kt += 64) {
            // stage 1: gload att rows [kt, kt+64) x p [m0, m0+256) -> T[l][p]
            // wave w covers T rows w*8 .. w*8+7 (contiguous flat segments)
            #pragma unroll
            for (int c = 0; c < 4; c++) {
                gload_lds16(A + (long)(kt + w6 * 8 + c * 2 + i5) * 1024
                              + m0 + (tid & 31) * 8,
                            &T[w6 * 2048 + c * 512]);
            }
            // B staging: l2t k-minor via gload + XOR
            #pragma unroll
            for (int c = 0; c < 2; c++)
                gload_lds16(B + (long)(c * 64 + srow) * 256 + kt + cg * 8,
                            &Bs[bldsbase + c * 64 * 64]);
            __syncthreads();

            // stage 2: transpose T -> As (XOR chunk swizzle).
            // wave w owns l-chunk w; lanes along p (conflict-free reads).
            #pragma unroll
            for (int pass = 0; pass < 4; pass++) {
                const int p = pass * 64 + (tid & 63);
                union { u16 e[8]; u32x4 v; } tmp;
                #pragma unroll
                for (int e = 0; e < 8; e++)
                    tmp.e[e] = T[(w6 * 8 + e) * 256 + p];
                *(u32x4*)&As[p * 64 + ((w6 ^ (p & 7)) * 8)] = tmp.v;
            }
            __syncthreads();

            // stage 3: MFMA (XOR reads, proven conflict-free)
            #pragma unroll
            for (int s = 0; s < 2; s++) {
                const int cp = ((s * 4 + q) ^ (li & 7)) * 8;
                bf16x8 av[4], bv[4];
                #pragma unroll
                for (int i = 0; i < 4; i++)
                    av[i] = *(bf16x8*)&As[(wr * 64 + i * 16 + li) * 64 + cp];
                #pragma unroll
                for (int j = 0; j < 4; j++)
                    bv[j] = *(bf16x8*)&Bs[(wc * 64 + j * 16 + li) * 64 + cp];
                #pragma unroll
                for (int i = 0; i < 4; i++)
                    #pragma unroll
                    for (int j = 0; j < 4; j++)
                        acc[i][j] = mfma16(av[i], bv[j], acc[i][j]);
            }
            __syncthreads();
        }

        const long obase = ((long)(bh >> 3) * 1024 + m0) * 1024 + (long)(bh & 7) * 128;
        #pragma unroll
        for (int i = 0; i < 4; i++)
            #pragma unroll
            for (int j = 0; j < 4; j++) {
                const int col = wc * 64 + j * 16 + li;
                #pragma unroll
                for (int r = 0; r < 4; r++) {
                    const int row = wr * 64 + i * 16 + q * 4 + r;
                    prot3[obase + (long)row * 1024 + col] = f2u(acc[i][j][r]);
                }
            }
    }
}

// ---------------------------------------------------------------------------
// Merged finals: out = relu([X, resid] @ Wst^T + bc), K = 1024+128 (STACK).
// grid (1, 160): y<32 lig -> out0, else prot -> out1. fp32 out, ldOut=128.
// ---------------------------------------------------------------------------
__global__ __launch_bounds__(256)
void finals_kernel(const u16* __restrict__ lig3, const u16* __restrict__ ligb,
                   const u16* __restrict__ WstL, const float* __restrict__ bcL,
                   float* __restrict__ out0,
                   const u16* __restrict__ prot3, const u16* __restrict__ protb,
                   const u16* __restrict__ WstP, const float* __restrict__ bcP,
                   float* __restrict__ out1)
{
    __shared__ __align__(16) u16 As[128 * 64];
    __shared__ __align__(16) u16 Bs[128 * 64];
    const int y = blockIdx.y;
    const u16 *A, *A2, *B; const float* bias; float* Out; int my;
    if (y < 32) { A = lig3;  A2 = ligb;  B = WstL; bias = bcL; Out = out0; my = y; }
    else        { A = prot3; A2 = protb; B = WstP; bias = bcP; Out = out1; my = y - 32; }
    const int m0 = my * 128;
    const int tid = threadIdx.x;
    const int w = tid >> 6, lane = tid & 63, q = lane >> 4, li = lane & 15;
    const int wr = w >> 1, wc = w & 1;

    const int srow = tid >> 3;
    const int cg = (tid & 7) ^ (srow & 7);
    const int ldsbase = ((tid >> 6) * 8) * 64;

    f32x4 acc[4][4];
    #pragma unroll
    for (int i = 0; i < 4; i++)
        #pragma unroll
        for (int j = 0; j < 4; j++) acc[i][j] = (f32x4){0.f, 0.f, 0.f, 0.f};

    for (int kt = 0; kt < 1152; kt += 64) {
        const u16* Abase; long lda; int ktA;
        if (kt >= 1024) { Abase = A2; lda = 128; ktA = kt - 1024; }
        else            { Abase = A;  lda = 1024; ktA = kt; }
        const u16* Ab = Abase + (long)m0 * lda + ktA + cg * 8;
        const u16* Bb = B + kt + cg * 8;          // n0 = 0, ld 1152
        #pragma unroll
        for (int c = 0; c < 4; c++) {
            gload_lds16(Ab + (long)(c * 32 + srow) * lda,  &As[ldsbase + c * 32 * 64]);
            gload_lds16(Bb + (long)(c * 32 + srow) * 1152, &Bs[ldsbase + c * 32 * 64]);
        }
        __syncthreads();
        #pragma unroll
        for (int s = 0; s < 2; s++) {
            const int cp = ((s * 4 + q) ^ (li & 7)) * 8;
            bf16x8 av[4], bv[4];
            #pragma unroll
            for (int i = 0; i < 4; i++)
                av[i] = *(bf16x8*)&As[(wr * 64 + i * 16 + li) * 64 + cp];
            #pragma unroll
            for (int j = 0; j < 4; j++)
                bv[j] = *(bf16x8*)&Bs[(wc * 64 + j * 16 + li) * 64 + cp];
            #pragma unroll
            for (int i = 0; i < 4; i++)
                #pragma unroll
                for (int j = 0; j < 4; j++)
                    acc[i][j] = mfma16(av[i], bv[j], acc[i][j]);
        }
        __syncthreads();
    }

    #pragma unroll
    for (int i = 0; i < 4; i++)
        #pragma unroll
        for (int j = 0; j < 4; j++) {
            const int col = wc * 64 + j * 16 + li;
            const float bvs = bias[col];
            #pragma unroll
            for (int r = 0; r < 4; r++) {
                const int row = m0 + wr * 64 + i * 16 + q * 4 + r;
                Out[(long)row * 128 + col] = fmaxf(acc[i][j][r] + bvs, 0.f);
            }
        }
}

// ---------------------------------------------------------------------------
// Attention v3: QBLK=32 rows per block, 512 threads, grid 1024 (1-D, XCD-
// swizzled: id%8 = XCD, the 8 m-tiles of one bh are CONSECUTIVE blocks on one
// XCD -> p1 panel (256 KB) fetched from HBM once, then L2-hits; ~8 panels
// (2 MB) live per 4 MB XCD-L2).
// Phase 1 (GEMM-style): p1 tile [64 p][128 d] staged in LDS (proj-pattern XOR
//   swizzle, shared by both 16-row groups), l1 rows in regs. 16 p-tiles,
//   4 MFMA each; S[32][1024] bf16 in LDS, phys col = col ^ ((row>>2)<<4)
//   (conflict-free writes and b128 row reads, proven in v2).
// Phases 2-4: row = tid>>4 owns a full 1024-wide row; inter multiply
//   (coalesced bf16x8), shfl-reduce max, exp-sum, normalized vector store.
// LDS = 64 KB (S) + 16 KB (p1) = 80 KB -> 2 blocks/CU (16 waves).
// ---------------------------------------------------------------------------
__global__ __launch_bounds__(512, 4)
void attn_kernel(const u16* __restrict__ l1, const u16* __restrict__ p1,
                 const u16* __restrict__ interb, u16* __restrict__ att)
{
    __shared__ __align__(16) u16 S[32 * 1024];   // 64 KB, swizzled bf16 scores
    __shared__ __align__(16) u16 Bs[2][64 * 64]; // 16 KB p1 tile (2 d-panels)
    const int id = blockIdx.x;
    const int bh = (id & 7) * 16 + (id >> 6);    // XCD id&7 owns bh block
    const int mt = (id >> 3) & 7;
    const int b  = bh >> 3;
    const int m0 = mt * 32;
    const int tid = threadIdx.x;
    const float rscale = 0.08838834764831845f; // 1/sqrt(128)

    // ---- phase 1: S = (l1 . p1) * rscale via LDS-staged p1 ----
    {
        const int w = tid >> 6, lane = tid & 63, q = lane >> 4, li = lane & 15;
        const int rgrp = w >> 2, pc = w & 3;     // row-group 0/1, p-col 0..3
        const int srow = tid >> 3;               // 0..63 (staging row)
        const int cg = (tid & 7) ^ (srow & 7);   // XOR chunk for staging
        bf16x8 af[4];
        const u16* lp = l1 + ((long)bh * 256 + m0 + rgrp * 16 + li) * 128 + q * 8;
        #pragma unroll
        for (int s = 0; s < 4; s++) af[s] = *(const bf16x8*)(lp + s * 32);
        const int sw = (rgrp * 4 + q) << 4;      // = (local_row>>2)<<4
        const u16* pbase = p1 + ((long)bh * 1024 + srow) * 128 + cg * 8;
        u16* ldst = &Bs[0][(tid >> 6) * 8 * 64]; // wave-uniform dest base

        for (int pt = 0; pt < 16; pt++) {
            // stage p1 rows [pt*64, pt*64+64) x d[0:128) as 2 panels of 64
            gload_lds16(pbase + (long)pt * 8192,      ldst);
            gload_lds16(pbase + (long)pt * 8192 + 64, ldst + 64 * 64);
            __syncthreads();
            f32x4 acc = (f32x4){0.f, 0.f, 0.f, 0.f};
            #pragma unroll
            for (int ks = 0; ks < 4; ks++) {
                bf16x8 bv = *(bf16x8*)&Bs[ks >> 1][(pc * 16 + li) * 64
                              + ((((ks & 1) * 4 + q) ^ (li & 7)) * 8)];
                acc = mfma16(af[ks], bv, acc);
            }
            const int col = pt * 64 + pc * 16 + li;
            const int lr0 = rgrp * 16 + q * 4;
            #pragma unroll
            for (int r = 0; r < 4; r++)
                S[((lr0 + r) << 10) + (col ^ sw)] = f2u(acc[r] * rscale);
            __syncthreads();
        }
    }

    // ---- phases 2-4: each row owned by one 16-lane group ----
    const int row = tid >> 4;          // 0..31
    const int lj  = tid & 15;          // column chunk within row
    const int l   = m0 + row;
    const int sw2 = (row >> 2) << 4;
    const u16* ib = interb + ((long)b * 256 + l) * 1024;

    // phase 2: multiply by inter (coalesced bf16x8), write back, row max
    float mx = -1e30f;
    #pragma unroll
    for (int blk = 0; blk < 8; blk++) {
        const int c = blk * 128 + lj * 8;
        u16* sp = &S[(row << 10) + (c ^ sw2)];
        u16x8 s8 = *(u16x8*)sp;
        u16x8 i8 = *(const u16x8*)(ib + c);
        u16x8 o8;
        #pragma unroll
        for (int e = 0; e < 8; e++) {
            float v = u2f(s8[e]) * u2f(i8[e]);
            mx = fmaxf(mx, v);
            o8[e] = f2u(v);
        }
        *(u16x8*)sp = o8;
    }
    #pragma unroll
    for (int d = 1; d < 16; d <<= 1) mx = fmaxf(mx, __shfl_xor(mx, d, 64));

    // phase 3: sum of exp
    float z = 0.f;
    #pragma unroll
    for (int blk = 0; blk < 8; blk++) {
        const int c = blk * 128 + lj * 8;
        u16x8 p8 = *(u16x8*)&S[(row << 10) + (c ^ sw2)];
        #pragma unroll
        for (int e = 0; e < 8; e++) z += __expf(u2f(p8[e]) - mx);
    }
    #pragma unroll
    for (int d = 1; d < 16; d <<= 1) z += __shfl_xor(z, d, 64);
    const float inv = 1.f / z;

    // phase 4: normalize + vectorized store
    u16* op = att + ((long)bh * 256 + l) * 1024;
    #pragma unroll
    for (int blk = 0; blk < 8; blk++) {
        const int c = blk * 128 + lj * 8;
        u16x8 p8 = *(u16x8*)&S[(row << 10) + (c ^ sw2)];
        u16x8 o8;
        #pragma unroll
        for (int e = 0; e < 8; e++)
            o8[e] = f2u(__expf(u2f(p8[e]) - mx) * inv);
        *(u16x8*)(op + c) = o8;
    }
}

// ---------------------------------------------------------------------------
// Fused 8-way transpose + fp32->bf16 convert for weights: dst[C,R] = bf16(src^T)
// ---------------------------------------------------------------------------
struct TPF { const float* src; u16* dst; int R; int C; };
struct TPF8 { TPF t[8]; };

__global__ __launch_bounds__(256)
void cvtw_kernel(TPF8 args)
{
    TPF tp = args.t[blockIdx.z];
    const int c0 = blockIdx.x * 32, r0 = blockIdx.y * 32;
    if (c0 >= tp.C || r0 >= tp.R) return;
    __shared__ u16 tile[32][33];
    const int tx = threadIdx.x & 31, ty = threadIdx.x >> 5;
    #pragma unroll
    for (int i = 0; i < 4; i++)
        tile[ty + i * 8][tx] = f2u(tp.src[(long)(r0 + ty + i * 8) * tp.C + c0 + tx]);
    __syncthreads();
    #pragma unroll
    for (int i = 0; i < 4; i++)
        tp.dst[(long)(c0 + ty + i * 8) * tp.R + r0 + tx] = tile[tx][ty + i * 8];
}

// ---------------------------------------------------------------------------
// Weight-combine: Wst[n][0:1024] = Wout_t[n][0:128] @ Wmid_t; tail = resid W;
// bc[n] = bout[n] + bmid . Wout_t[n][0:128].
// ---------------------------------------------------------------------------
__global__ __launch_bounds__(256)
void wcomb_kernel(const u16* __restrict__ Wm0, const u16* __restrict__ Wo0,
                  const float* __restrict__ bm0, const float* __restrict__ bo0,
                  u16* __restrict__ Wst0, float* __restrict__ bc0,
                  const u16* __restrict__ Wm1, const u16* __restrict__ Wo1,
                  const float* __restrict__ bm1, const float* __restrict__ bo1,
                  u16* __restrict__ Wst1, float* __restrict__ bc1)
{
    const int zz = blockIdx.y;
    const u16* Wm = zz ? Wm1 : Wm0;
    const u16* Wo = zz ? Wo1 : Wo0;
    const float* bmid = zz ? bm1 : bm0;
    const float* bout = zz ? bo1 : bo0;
    u16* Wst = zz ? Wst1 : Wst0;
    float* bc = zz ? bc1 : bc0;
    const int n = blockIdx.x;
    const int tid = threadIdx.x;
    __shared__ float wrow[128];
    if (tid < 128) wrow[tid] = u2f(Wo[n * 256 + tid]);
    __syncthreads();
    for (int k = tid; k < 1024; k += 256) {
        float acc = 0.f;
        #pragma unroll 4
        for (int j = 0; j < 128; j++) acc += wrow[j] * u2f(Wm[(long)j * 1024 + k]);
        Wst[(long)n * 1152 + k] = f2u(acc);
    }
    if (tid < 128) Wst[(long)n * 1152 + 1024 + tid] = Wo[n * 256 + 128 + tid];
    if (tid == 0) {
        float acc = bout[n];
        for (int j = 0; j < 128; j++) acc += bmid[j] * wrow[j];
        bc[n] = acc;
    }
}

// ---------------------------------------------------------------------------
// fp32 -> bf16 converts: z=0 ligand, z=1 prot, z=2 inter
// ---------------------------------------------------------------------------
__global__ __launch_bounds__(256)
void cvt3_kernel(const float* __restrict__ a, u16* __restrict__ da, int na,
                 const float* __restrict__ b, u16* __restrict__ db, int nb,
                 const float* __restrict__ c, u16* __restrict__ dc, int nc)
{
    const int zz = blockIdx.y;
    const float* s = zz == 0 ? a : (zz == 1 ? b : c);
    u16* d = zz == 0 ? da : (zz == 1 ? db : dc);
    const int n = zz == 0 ? na : (zz == 1 ? nb : nc);
    const int i = (blockIdx.x * 256 + threadIdx.x) * 4;
    if (i >= n) return;
    const float4 v = *(const float4*)(s + i);
    u16x4 o;
    o.x = f2u(v.x); o.y = f2u(v.y); o.z = f2u(v.z); o.w = f2u(v.w);
    *(u16x4*)(d + i) = o;
}

// ---------------------------------------------------------------------------
extern "C" void kernel_launch(void* const* d_in, const int* in_sizes, int n_in,
                              void* d_out, int out_size, void* d_ws, size_t ws_size,
                              hipStream_t stream)
{
    (void)in_sizes; (void)n_in; (void)out_size; (void)ws_size;
    const float* ligand = (const float*)d_in[0];
    const float* prot   = (const float*)d_in[1];
    const float* inter  = (const float*)d_in[2];
    const float* Wl1 = (const float*)d_in[3];  const float* bl1 = (const float*)d_in[4];
    const float* Wl2 = (const float*)d_in[5];  const float* bl2 = (const float*)d_in[6];
    const float* Wp1 = (const float*)d_in[7];  const float* bp1 = (const float*)d_in[8];
    const float* Wp2 = (const float*)d_in[9];  const float* bp2 = (const float*)d_in[10];
    const float* W11 = (const float*)d_in[11]; const float* b11 = (const float*)d_in[12];
    const float* W12 = (const float*)d_in[13]; const float* b12 = (const float*)d_in[14];
    const float* W21 = (const float*)d_in[15]; const float* b21 = (const float*)d_in[16];
    const float* W22 = (const float*)d_in[17]; const float* b22 = (const float*)d_in[18];

    float* out0 = (float*)d_out;                    // [16,256,128]
    float* out1 = out0 + (size_t)16 * 256 * 128;    // [16,1024,128]

    u16* ws = (u16*)d_ws;
    size_t off = 0;
    auto alloc = [&](size_t n) { u16* p = ws + off; off += n; return p; };
    u16* ligb  = alloc(524288);    // bf16 ligand [4096,128]
    u16* protb = alloc(2097152);   // bf16 prot  [16384,128]
    u16* l1v   = alloc(4194304);   // [16,8,256,128]
    u16* l2t   = alloc(4194304);   // [16,8,128,256]  (head-T)
    u16* p1v   = alloc(16777216);  // [16,8,1024,128]
    u16* p2t   = alloc(16777216);  // [16,8,128,1024] (head-T)
    u16* attv  = alloc(33554432);  // [16,8,256,1024]
    u16* lig3  = alloc(4194304);   // [16,256,1024]
    u16* prot3 = alloc(16777216);  // [16,1024,1024]
    u16* Wl1t  = alloc(131072);    // [1024,128]
    u16* Wl2t  = alloc(131072);
    u16* Wp1t  = alloc(131072);
    u16* Wp2t  = alloc(131072);
    u16* W11t  = alloc(131072);    // [128,1024] = W11^T
    u16* W21t  = alloc(131072);    // [128,1024] = W21^T
    u16* W12t  = alloc(32768);     // [128,256]  = W12^T
    u16* W22t  = alloc(32768);     // [128,256]  = W22^T
    u16* WstL  = alloc(147456);    // [128,1152] combined lig weight
    u16* WstP  = alloc(147456);    // [128,1152] combined prot weight
    float* bcL = (float*)alloc(256);  // [128] f32
    float* bcP = (float*)alloc(256);  // [128] f32

    // interb aliases lig3: interb is consumed by attn_kernel, which completes
    // before av_kernel writes lig3 (stream-ordered). Sizes match exactly
    // (16*256*1024 u16).
    u16* interb = lig3;

    // input conversion (ligand, prot, inter) -> bf16
    cvt3_kernel<<<dim3(4096, 3), 256, 0, stream>>>(
        ligand, ligb, 524288, prot, protb, 2097152, inter, interb, 4194304);

    TPF8 tp;
    tp.t[0] = {Wl1, Wl1t, 128, 1024};
    tp.t[1] = {Wl2, Wl2t, 128, 1024};
    tp.t[2] = {Wp1, Wp1t, 128, 1024};
    tp.t[3] = {Wp2, Wp2t, 128, 1024};
    tp.t[4] = {W11, W11t, 1024, 128};
    tp.t[5] = {W21, W21t, 1024, 128};
    tp.t[6] = {W12, W12t, 256, 128};
    tp.t[7] = {W22, W22t, 256, 128};
    cvtw_kernel<<<dim3(32, 32, 8), 256, 0, stream>>>(tp);

    // combine W11@W12top / W21@W22top + residual halves + biases
    wcomb_kernel<<<dim3(128, 2), 256, 0, stream>>>(
        W11t, W12t, b11, b12, WstL, bcL,
        W21t, W22t, b21, b22, WstP, bcP);

    // all four projections in one dispatch
    proj_kernel<<<dim3(8, 320), 256, 0, stream>>>(
        ligb, protb, Wl1t, Wl2t, Wp1t, Wp2t,
        bl1, bl2, bp1, bp2, l1v, l2t, p1v, p2t);

    // attention scores + softmax (QBLK=32, LDS-staged p1, XCD-grouped grid)
    attn_kernel<<<dim3(1024), 512, 0, stream>>>(l1v, p1v, interb, attv);

    // both AV GEMMs in one dispatch (conflict-free prot transpose staging)
    av_kernel<<<dim3(640), 512, 0, stream>>>(attv, p2t, l2t, lig3, prot3);

    // both fused finals in one dispatch
    finals_kernel<<<dim3(1, 160), 256, 0, stream>>>(
        lig3, ligb, WstL, bcL, out0,
        prot3, protb, WstP, bcP, out1);
}